// Round 1
// baseline (84.082 us; speedup 1.0000x reference)
//
#include <hip/hip_runtime.h>

#define NB 8
#define NN 2048
#define FIN 256
#define FOUT 128

typedef __attribute__((ext_vector_type(8))) short short8;
typedef __attribute__((ext_vector_type(4))) float f32x4;

static __device__ __forceinline__ unsigned short f2bf(float f) {
    unsigned int u = __float_as_uint(f);
    u += 0x7fffu + ((u >> 16) & 1u);
    return (unsigned short)(u >> 16);
}

// K1: Wh = h@W (fp32 in regs), emit s1/s2 (fp32) and WhPV (bf16, MFMA-B-fragment layout).
// WhPV layout per 64-j chunk: [kt(2)][nt(8)][lane(64)][i(8)] where element =
//   Wh[j0 + 32*kt + 8*(lane>>4) + i][16*nt + (lane&15)]   (sigma(g,i) = 8g+i)
__global__ __launch_bounds__(256) void gat_prep(
    const float* __restrict__ h, const float* __restrict__ W, const float* __restrict__ a,
    unsigned short* __restrict__ whpv, float* __restrict__ s1g, float* __restrict__ s2g)
{
    __shared__ __align__(16) float hT[64 * FIN];        // 64 KB
    __shared__ __align__(16) unsigned short pvs[8192];  // 16 KB
    const int t = threadIdx.x;
    const int bx = blockIdx.x;
    const int b = bx >> 5;
    const int jt = bx & 31;
    const int j0 = jt * 64;

    // stage h tile [64][256]
    const float* hsrc = h + ((size_t)b * NN + j0) * FIN;
    #pragma unroll
    for (int p = 0; p < 16; ++p) {
        int idx = p * 256 + t;
        *(f32x4*)&hT[idx * 4] = *(const f32x4*)&hsrc[idx * 4];
    }
    __syncthreads();

    const int cg = t & 31;   // cols 4cg..4cg+3
    const int rg = t >> 5;   // rows 8rg..8rg+7
    float acc[8][4];
    #pragma unroll
    for (int r = 0; r < 8; ++r)
        #pragma unroll
        for (int q = 0; q < 4; ++q) acc[r][q] = 0.f;

    for (int f = 0; f < FIN; f += 4) {
        f32x4 wv[4];
        #pragma unroll
        for (int q = 0; q < 4; ++q) wv[q] = *(const f32x4*)&W[(f + q) * FOUT + cg * 4];
        #pragma unroll
        for (int r = 0; r < 8; ++r) {
            f32x4 hv = *(const f32x4*)&hT[(rg * 8 + r) * FIN + f];
            #pragma unroll
            for (int q = 0; q < 4; ++q) {
                acc[r][0] += hv[q] * wv[q][0];
                acc[r][1] += hv[q] * wv[q][1];
                acc[r][2] += hv[q] * wv[q][2];
                acc[r][3] += hv[q] * wv[q][3];
            }
        }
    }

    // s1/s2: per-row dot with a1/a2, reduce across the 32 cg lanes (half-wave)
    f32x4 a1v = *(const f32x4*)&a[cg * 4];
    f32x4 a2v = *(const f32x4*)&a[FOUT + cg * 4];
    #pragma unroll
    for (int r = 0; r < 8; ++r) {
        float p1 = acc[r][0]*a1v[0] + acc[r][1]*a1v[1] + acc[r][2]*a1v[2] + acc[r][3]*a1v[3];
        float p2 = acc[r][0]*a2v[0] + acc[r][1]*a2v[1] + acc[r][2]*a2v[2] + acc[r][3]*a2v[3];
        #pragma unroll
        for (int m = 16; m >= 1; m >>= 1) {
            p1 += __shfl_xor(p1, m, 64);
            p2 += __shfl_xor(p2, m, 64);
        }
        if (cg == 0) {
            s1g[b * NN + j0 + rg * 8 + r] = p1;
            s2g[b * NN + j0 + rg * 8 + r] = p2;
        }
    }

    // pack WhPV bf16 into LDS in fragment layout, then coalesced copy out
    #pragma unroll
    for (int r = 0; r < 8; ++r) {
        int jl = rg * 8 + r;
        int kt = jl >> 5, j5 = jl & 31, g = j5 >> 3, i = j5 & 7;
        #pragma unroll
        for (int q = 0; q < 4; ++q) {
            int c = cg * 4 + q;
            int lane = g * 16 + (c & 15);
            int nt = c >> 4;
            pvs[((kt * 8 + nt) * 64 + lane) * 8 + i] = f2bf(acc[r][q]);
        }
    }
    __syncthreads();
    unsigned short* dst = whpv + (size_t)(b * 32 + jt) * 8192;
    #pragma unroll
    for (int p = 0; p < 4; ++p) {
        int idx = p * 2048 + t * 8;
        *(short8*)&dst[idx] = *(const short8*)&pvs[idx];
    }
}

// K2: per 64-row i-tile: loop j-chunks of 64: P = masked exp(lrelu(s1+s2)) -> LDS (bf16,
// XOR-swizzled), S += rowsum(P); OUT += P @ WhPV via mfma_f32_16x16x32_bf16; finally OUT/S.
__global__ __launch_bounds__(512) void gat_main(
    const int* __restrict__ adj, const unsigned short* __restrict__ whpv,
    const float* __restrict__ s1g, const float* __restrict__ s2g, float* __restrict__ out)
{
    __shared__ __align__(16) char Plds[64 * 128];       // 8 KB: [row][slot^ (16B)]
    __shared__ __align__(16) unsigned short BL[8192];   // 16 KB: B fragments
    __shared__ float Sden[64];

    const int t = threadIdx.x;
    const int bx = blockIdx.x;
    const int b = bx >> 5;
    const int i0 = (bx & 31) * 64;

    // P-compute mapping: jp = j-pair (2 j's), rq -> rows 4rq..4rq+3
    const int jp = t & 31;
    const int rq = t >> 5;

    // MFMA mapping: 8 waves, wave w: M-tile mt = w>>1, N-tiles ntb..ntb+3
    const int lane = t & 63;
    const int w = t >> 6;
    const int mt = w >> 1;
    const int ntb = (w & 1) * 4;
    const int arow = mt * 16 + (lane & 15);
    const int g = lane >> 4;

    float s1v[4];
    #pragma unroll
    for (int k = 0; k < 4; ++k) s1v[k] = s1g[b * NN + i0 + rq * 4 + k];

    f32x4 acc[4];
    #pragma unroll
    for (int nt = 0; nt < 4; ++nt) acc[nt] = (f32x4){0.f, 0.f, 0.f, 0.f};
    float ssum[4] = {0.f, 0.f, 0.f, 0.f};

    const int* adjb = adj + (size_t)b * NN * NN + (size_t)i0 * NN;
    const unsigned short* whb = whpv + (size_t)b * 32 * 8192;
    const float* s2b = s2g + b * NN;

    for (int j0 = 0; j0 < NN; j0 += 64) {
        // stage next B chunk into regs early (latency hides under P compute)
        const unsigned short* wsrc = whb + (size_t)(j0 >> 6) * 8192;
        short8 st0 = *(const short8*)&wsrc[t * 8];
        short8 st1 = *(const short8*)&wsrc[4096 + t * 8];

        // compute P tile (64 x 64)
        #pragma unroll
        for (int k = 0; k < 4; ++k) {
            int r = rq * 4 + k;
            int2 av = *(const int2*)&adjb[(size_t)r * NN + j0 + jp * 2];
            float2 s2v = *(const float2*)&s2b[j0 + jp * 2];
            float e0 = s1v[k] + s2v.x;
            e0 = fmaxf(e0, 0.2f * e0);
            float p0 = (av.x > 0) ? __expf(e0) : 0.f;
            float e1 = s1v[k] + s2v.y;
            e1 = fmaxf(e1, 0.2f * e1);
            float p1 = (av.y > 0) ? __expf(e1) : 0.f;
            ssum[k] += p0 + p1;
            unsigned int pk = (unsigned int)f2bf(p0) | ((unsigned int)f2bf(p1) << 16);
            int slot = (jp >> 2) ^ (r & 7);
            *(unsigned int*)&Plds[r * 128 + slot * 16 + (jp & 3) * 4] = pk;
        }
        // write staged B to LDS
        *(short8*)&BL[t * 8] = st0;
        *(short8*)&BL[4096 + t * 8] = st1;
        __syncthreads();

        #pragma unroll
        for (int kt = 0; kt < 2; ++kt) {
            int aslot = (4 * kt + g) ^ (arow & 7);
            short8 af = *(const short8*)&Plds[arow * 128 + aslot * 16];
            #pragma unroll
            for (int nt = 0; nt < 4; ++nt) {
                short8 bfr = *(const short8*)&BL[((kt * 8 + ntb + nt) * 64 + lane) * 8];
                acc[nt] = __builtin_amdgcn_mfma_f32_16x16x32_bf16(af, bfr, acc[nt], 0, 0, 0);
            }
        }
        __syncthreads();
    }

    // softmax denominators: reduce ssum over the 32 jp lanes (stays in 32-lane half)
    #pragma unroll
    for (int k = 0; k < 4; ++k) {
        float v = ssum[k];
        #pragma unroll
        for (int m = 16; m >= 1; m >>= 1) v += __shfl_xor(v, m, 64);
        if (jp == 0) Sden[rq * 4 + k] = v;
    }
    __syncthreads();

    // epilogue: scale by 1/S and store. D layout: col = lane&15, row = (lane>>4)*4 + reg
    float* ob = out + ((size_t)b * NN + i0) * FOUT;
    #pragma unroll
    for (int nt = 0; nt < 4; ++nt) {
        int col = (ntb + nt) * 16 + (lane & 15);
        #pragma unroll
        for (int r = 0; r < 4; ++r) {
            int row = mt * 16 + (lane >> 4) * 4 + r;
            ob[(size_t)row * FOUT + col] = acc[nt][r] / Sden[row];
        }
    }
}

extern "C" void kernel_launch(void* const* d_in, const int* in_sizes, int n_in,
                              void* d_out, int out_size, void* d_ws, size_t ws_size,
                              hipStream_t stream) {
    (void)in_sizes; (void)n_in; (void)out_size; (void)ws_size;
    const float* h   = (const float*)d_in[0];
    const int*   adj = (const int*)d_in[1];
    const float* W   = (const float*)d_in[2];
    const float* a   = (const float*)d_in[3];
    float* out = (float*)d_out;

    unsigned short* whpv = (unsigned short*)d_ws;                       // 4 MB bf16 fragments
    float* s1g = (float*)((char*)d_ws + (4u << 20));                    // 64 KB
    float* s2g = (float*)((char*)d_ws + (4u << 20) + (64u << 10));     // 64 KB

    gat_prep<<<dim3(256), dim3(256), 0, stream>>>(h, W, a, whpv, s1g, s2g);
    gat_main<<<dim3(256), dim3(512), 0, stream>>>(adj, whpv, s1g, s2g, out);
}

// Round 2
// 79.467 us; speedup vs baseline: 1.0581x; 1.0581x over previous
//
#include <hip/hip_runtime.h>

#define NB 8
#define NN 2048
#define FIN 256
#define FOUT 128

typedef __attribute__((ext_vector_type(8))) short short8;
typedef __attribute__((ext_vector_type(4))) float f32x4;

static __device__ __forceinline__ unsigned short f2bf(float f) {
    unsigned int u = __float_as_uint(f);
    u += 0x7fffu + ((u >> 16) & 1u);
    return (unsigned short)(u >> 16);
}

// K1: Wh = h@W (fp32 in regs), emit s1/s2 (fp32) and WhPV (bf16, MFMA-B-fragment layout).
// WhPV layout per 64-j chunk: [kt(2)][nt(8)][lane(64)][i(8)] where element =
//   Wh[j0 + 32*kt + 8*(lane>>4) + i][16*nt + (lane&15)]   (sigma(g,i) = 8g+i)
__global__ __launch_bounds__(256) void gat_prep(
    const float* __restrict__ h, const float* __restrict__ W, const float* __restrict__ a,
    unsigned short* __restrict__ whpv, float* __restrict__ s1g, float* __restrict__ s2g)
{
    __shared__ __align__(16) float hT[64 * FIN];        // 64 KB
    __shared__ __align__(16) unsigned short pvs[8192];  // 16 KB
    const int t = threadIdx.x;
    const int bx = blockIdx.x;
    const int b = bx >> 5;
    const int jt = bx & 31;
    const int j0 = jt * 64;

    const float* hsrc = h + ((size_t)b * NN + j0) * FIN;
    #pragma unroll
    for (int p = 0; p < 16; ++p) {
        int idx = p * 256 + t;
        *(f32x4*)&hT[idx * 4] = *(const f32x4*)&hsrc[idx * 4];
    }
    __syncthreads();

    const int cg = t & 31;   // cols 4cg..4cg+3
    const int rg = t >> 5;   // rows 8rg..8rg+7
    float acc[8][4];
    #pragma unroll
    for (int r = 0; r < 8; ++r)
        #pragma unroll
        for (int q = 0; q < 4; ++q) acc[r][q] = 0.f;

    for (int f = 0; f < FIN; f += 4) {
        f32x4 wv[4];
        #pragma unroll
        for (int q = 0; q < 4; ++q) wv[q] = *(const f32x4*)&W[(f + q) * FOUT + cg * 4];
        #pragma unroll
        for (int r = 0; r < 8; ++r) {
            f32x4 hv = *(const f32x4*)&hT[(rg * 8 + r) * FIN + f];
            #pragma unroll
            for (int q = 0; q < 4; ++q) {
                acc[r][0] += hv[q] * wv[q][0];
                acc[r][1] += hv[q] * wv[q][1];
                acc[r][2] += hv[q] * wv[q][2];
                acc[r][3] += hv[q] * wv[q][3];
            }
        }
    }

    f32x4 a1v = *(const f32x4*)&a[cg * 4];
    f32x4 a2v = *(const f32x4*)&a[FOUT + cg * 4];
    #pragma unroll
    for (int r = 0; r < 8; ++r) {
        float p1 = acc[r][0]*a1v[0] + acc[r][1]*a1v[1] + acc[r][2]*a1v[2] + acc[r][3]*a1v[3];
        float p2 = acc[r][0]*a2v[0] + acc[r][1]*a2v[1] + acc[r][2]*a2v[2] + acc[r][3]*a2v[3];
        #pragma unroll
        for (int m = 16; m >= 1; m >>= 1) {
            p1 += __shfl_xor(p1, m, 64);
            p2 += __shfl_xor(p2, m, 64);
        }
        if (cg == 0) {
            s1g[b * NN + j0 + rg * 8 + r] = p1;
            s2g[b * NN + j0 + rg * 8 + r] = p2;
        }
    }

    #pragma unroll
    for (int r = 0; r < 8; ++r) {
        int jl = rg * 8 + r;
        int kt = jl >> 5, j5 = jl & 31, g = j5 >> 3, i = j5 & 7;
        #pragma unroll
        for (int q = 0; q < 4; ++q) {
            int c = cg * 4 + q;
            int lane = g * 16 + (c & 15);
            int nt = c >> 4;
            pvs[((kt * 8 + nt) * 64 + lane) * 8 + i] = f2bf(acc[r][q]);
        }
    }
    __syncthreads();
    unsigned short* dst = whpv + (size_t)(b * 32 + jt) * 8192;
    #pragma unroll
    for (int p = 0; p < 4; ++p) {
        int idx = p * 2048 + t * 8;
        *(short8*)&dst[idx] = *(const short8*)&pvs[idx];
    }
}

// K2 v2: 32-row i-tiles (512 blocks = 2/CU), double-buffered LDS, single barrier/iter,
// 1-deep register prefetch of adj (int4/thread) and Wh fragments.
__global__ __launch_bounds__(512, 4) void gat_main(
    const int* __restrict__ adj, const unsigned short* __restrict__ whpv,
    const float* __restrict__ s1g, const float* __restrict__ s2g, float* __restrict__ out)
{
    __shared__ __align__(16) char Plds[2][32 * 128];       // 2 x 4 KB: [row][slot^ (16B)]
    __shared__ __align__(16) unsigned short BL[2][8192];   // 2 x 16 KB: B fragments
    __shared__ float Sden[32];

    const int t = threadIdx.x;
    const int bx = blockIdx.x;
    const int b = bx >> 6;
    const int i0 = (bx & 63) * 32;

    // P-compute mapping: one row x 4 j's per thread
    const int r  = t >> 4;   // row 0..31
    const int jq = t & 15;   // j quad -> j = 4*jq .. 4*jq+3

    // MFMA mapping: 8 waves; wave w: M-tile mt = w&1, N-tiles {2*nb, 2*nb+1}, nb = w>>1
    const int lane = t & 63;
    const int w = t >> 6;
    const int mt = w & 1;
    const int nb = w >> 1;
    const int arow = mt * 16 + (lane & 15);
    const int g = lane >> 4;

    const float s1v = s1g[b * NN + i0 + r];

    f32x4 acc[2];
    acc[0] = (f32x4){0.f, 0.f, 0.f, 0.f};
    acc[1] = (f32x4){0.f, 0.f, 0.f, 0.f};
    float ssum = 0.f;

    const int* adjb = adj + (size_t)b * NN * NN + (size_t)i0 * NN;
    const int* aptr = adjb + (size_t)r * NN + jq * 4;
    const unsigned short* whb = whpv + (size_t)b * 32 * 8192;
    const float* s2b = s2g + b * NN;

    // prologue: prefetch chunk 0
    int4 ac = *(const int4*)aptr;
    short8 wc0 = *(const short8*)&whb[t * 8];
    short8 wc1 = *(const short8*)&whb[4096 + t * 8];

    const int pbyte = r * 128 + ((jq >> 1) ^ (r & 7)) * 16 + (jq & 1) * 8;
    const int abyte = arow * 128;
    int buf = 0;

    for (int jc = 0; jc < 32; ++jc) {
        // issue next-chunk prefetch (wraps harmlessly at the end)
        const int jn = (jc + 1) & 31;
        int4 an = *(const int4*)(aptr + jn * 64);
        const unsigned short* wn = whb + (size_t)jn * 8192;
        short8 wn0 = *(const short8*)&wn[t * 8];
        short8 wn1 = *(const short8*)&wn[4096 + t * 8];

        // compute P (32x64) for current chunk from prefetched regs
        f32x4 s2v = *(const f32x4*)&s2b[jc * 64 + jq * 4];
        float p[4];
        {
            float e0 = s1v + s2v[0]; e0 = fmaxf(e0, 0.2f * e0);
            p[0] = (ac.x > 0) ? __expf(e0) : 0.f;
            float e1 = s1v + s2v[1]; e1 = fmaxf(e1, 0.2f * e1);
            p[1] = (ac.y > 0) ? __expf(e1) : 0.f;
            float e2 = s1v + s2v[2]; e2 = fmaxf(e2, 0.2f * e2);
            p[2] = (ac.z > 0) ? __expf(e2) : 0.f;
            float e3 = s1v + s2v[3]; e3 = fmaxf(e3, 0.2f * e3);
            p[3] = (ac.w > 0) ? __expf(e3) : 0.f;
        }
        ssum += (p[0] + p[1]) + (p[2] + p[3]);
        unsigned int pk0 = (unsigned int)f2bf(p[0]) | ((unsigned int)f2bf(p[1]) << 16);
        unsigned int pk1 = (unsigned int)f2bf(p[2]) | ((unsigned int)f2bf(p[3]) << 16);
        uint2 pk = {pk0, pk1};
        *(uint2*)&Plds[buf][pbyte] = pk;

        // write current Wh fragments to LDS
        *(short8*)&BL[buf][t * 8] = wc0;
        *(short8*)&BL[buf][4096 + t * 8] = wc1;
        __syncthreads();

        // MFMA on current buffer
        #pragma unroll
        for (int kt = 0; kt < 2; ++kt) {
            int aslot = (4 * kt + g) ^ (arow & 7);
            short8 af = *(const short8*)&Plds[buf][abyte + aslot * 16];
            #pragma unroll
            for (int n = 0; n < 2; ++n) {
                int nt = nb * 2 + n;
                short8 bfr = *(const short8*)&BL[buf][((kt * 8 + nt) * 64 + lane) * 8];
                acc[n] = __builtin_amdgcn_mfma_f32_16x16x32_bf16(af, bfr, acc[n], 0, 0, 0);
            }
        }

        ac = an; wc0 = wn0; wc1 = wn1; buf ^= 1;
    }

    // softmax denominators: reduce over the 16 lanes sharing a row
    {
        float v = ssum;
        #pragma unroll
        for (int m = 8; m >= 1; m >>= 1) v += __shfl_xor(v, m, 64);
        if (jq == 0) Sden[r] = v;
    }
    __syncthreads();

    // epilogue: scale by 1/S, store. D layout: col = lane&15, row = (lane>>4)*4 + reg
    float* ob = out + ((size_t)b * NN + i0) * FOUT;
    #pragma unroll
    for (int n = 0; n < 2; ++n) {
        int col = (nb * 2 + n) * 16 + (lane & 15);
        #pragma unroll
        for (int q = 0; q < 4; ++q) {
            int row = mt * 16 + (lane >> 4) * 4 + q;
            ob[(size_t)row * FOUT + col] = acc[n][q] / Sden[row];
        }
    }
}

extern "C" void kernel_launch(void* const* d_in, const int* in_sizes, int n_in,
                              void* d_out, int out_size, void* d_ws, size_t ws_size,
                              hipStream_t stream) {
    (void)in_sizes; (void)n_in; (void)out_size; (void)ws_size;
    const float* h   = (const float*)d_in[0];
    const int*   adj = (const int*)d_in[1];
    const float* W   = (const float*)d_in[2];
    const float* a   = (const float*)d_in[3];
    float* out = (float*)d_out;

    unsigned short* whpv = (unsigned short*)d_ws;                       // 4 MB bf16 fragments
    float* s1g = (float*)((char*)d_ws + (4u << 20));                    // 64 KB
    float* s2g = (float*)((char*)d_ws + (4u << 20) + (64u << 10));     // 64 KB

    gat_prep<<<dim3(256), dim3(256), 0, stream>>>(h, W, a, whpv, s1g, s2g);
    gat_main<<<dim3(512), dim3(512), 0, stream>>>(adj, whpv, s1g, s2g, out);
}

// Round 3
// 75.845 us; speedup vs baseline: 1.1086x; 1.0478x over previous
//
#include <hip/hip_runtime.h>

#define NB 8
#define NN 2048
#define FIN 256
#define FOUT 128

typedef __attribute__((ext_vector_type(8))) short short8;
typedef __attribute__((ext_vector_type(4))) float f32x4;

static __device__ __forceinline__ unsigned short f2bf(float f) {
    unsigned int u = __float_as_uint(f);
    u += 0x7fffu + ((u >> 16) & 1u);
    return (unsigned short)(u >> 16);
}

// Raw barrier: LDS writes visible (lgkmcnt(0)), but outstanding GLOBAL loads are NOT
// drained (no vmcnt wait) — prefetch stays in flight across the barrier.
#define BAR_LGKM()                                            \
    do {                                                      \
        asm volatile("s_waitcnt lgkmcnt(0)" ::: "memory");    \
        __builtin_amdgcn_sched_barrier(0);                    \
        __builtin_amdgcn_s_barrier();                         \
        __builtin_amdgcn_sched_barrier(0);                    \
    } while (0)

// K1: Wh = h@W (fp32 in regs), emit s1/s2 (fp32) and WhPV (bf16, MFMA-B-fragment layout).
// WhPV layout per 64-j chunk: [kt(2)][nt(8)][lane(64)][i(8)] where element =
//   Wh[j0 + 32*kt + 8*(lane>>4) + i][16*nt + (lane&15)]   (sigma(g,i) = 8g+i)
__global__ __launch_bounds__(256) void gat_prep(
    const float* __restrict__ h, const float* __restrict__ W, const float* __restrict__ a,
    unsigned short* __restrict__ whpv, float* __restrict__ s1g, float* __restrict__ s2g)
{
    __shared__ __align__(16) float hT[64 * FIN];        // 64 KB
    __shared__ __align__(16) unsigned short pvs[8192];  // 16 KB
    const int t = threadIdx.x;
    const int bx = blockIdx.x;
    const int b = bx >> 5;
    const int jt = bx & 31;
    const int j0 = jt * 64;

    const float* hsrc = h + ((size_t)b * NN + j0) * FIN;
    #pragma unroll
    for (int p = 0; p < 16; ++p) {
        int idx = p * 256 + t;
        *(f32x4*)&hT[idx * 4] = *(const f32x4*)&hsrc[idx * 4];
    }
    __syncthreads();

    const int cg = t & 31;   // cols 4cg..4cg+3
    const int rg = t >> 5;   // rows 8rg..8rg+7
    float acc[8][4];
    #pragma unroll
    for (int r = 0; r < 8; ++r)
        #pragma unroll
        for (int q = 0; q < 4; ++q) acc[r][q] = 0.f;

    for (int f = 0; f < FIN; f += 4) {
        f32x4 wv[4];
        #pragma unroll
        for (int q = 0; q < 4; ++q) wv[q] = *(const f32x4*)&W[(f + q) * FOUT + cg * 4];
        #pragma unroll
        for (int r = 0; r < 8; ++r) {
            f32x4 hv = *(const f32x4*)&hT[(rg * 8 + r) * FIN + f];
            #pragma unroll
            for (int q = 0; q < 4; ++q) {
                acc[r][0] += hv[q] * wv[q][0];
                acc[r][1] += hv[q] * wv[q][1];
                acc[r][2] += hv[q] * wv[q][2];
                acc[r][3] += hv[q] * wv[q][3];
            }
        }
    }

    f32x4 a1v = *(const f32x4*)&a[cg * 4];
    f32x4 a2v = *(const f32x4*)&a[FOUT + cg * 4];
    #pragma unroll
    for (int r = 0; r < 8; ++r) {
        float p1 = acc[r][0]*a1v[0] + acc[r][1]*a1v[1] + acc[r][2]*a1v[2] + acc[r][3]*a1v[3];
        float p2 = acc[r][0]*a2v[0] + acc[r][1]*a2v[1] + acc[r][2]*a2v[2] + acc[r][3]*a2v[3];
        #pragma unroll
        for (int m = 16; m >= 1; m >>= 1) {
            p1 += __shfl_xor(p1, m, 64);
            p2 += __shfl_xor(p2, m, 64);
        }
        if (cg == 0) {
            s1g[b * NN + j0 + rg * 8 + r] = p1;
            s2g[b * NN + j0 + rg * 8 + r] = p2;
        }
    }

    #pragma unroll
    for (int r = 0; r < 8; ++r) {
        int jl = rg * 8 + r;
        int kt = jl >> 5, j5 = jl & 31, g = j5 >> 3, i = j5 & 7;
        #pragma unroll
        for (int q = 0; q < 4; ++q) {
            int c = cg * 4 + q;
            int lane = g * 16 + (c & 15);
            int nt = c >> 4;
            pvs[((kt * 8 + nt) * 64 + lane) * 8 + i] = f2bf(acc[r][q]);
        }
    }
    __syncthreads();
    unsigned short* dst = whpv + (size_t)(b * 32 + jt) * 8192;
    #pragma unroll
    for (int p = 0; p < 4; ++p) {
        int idx = p * 2048 + t * 8;
        *(short8*)&dst[idx] = *(const short8*)&pvs[idx];
    }
}

// K2 v3: 32-row i-tiles (512 blocks = 2/CU), double-buffered LDS, depth-2 register
// prefetch, raw s_barrier with lgkmcnt-only wait (global prefetch never drained).
__global__ __launch_bounds__(512, 4) void gat_main(
    const int* __restrict__ adj, const unsigned short* __restrict__ whpv,
    const float* __restrict__ s1g, const float* __restrict__ s2g, float* __restrict__ out)
{
    __shared__ __align__(16) char Plds[2][32 * 128];       // 2 x 4 KB: [row][slot^ (16B)]
    __shared__ __align__(16) unsigned short BL[2][8192];   // 2 x 16 KB: B fragments
    __shared__ float Sden[32];

    const int t = threadIdx.x;
    const int bx = blockIdx.x;
    const int b = bx >> 6;
    const int i0 = (bx & 63) * 32;

    // P-compute mapping: one row x 4 j's per thread
    const int r  = t >> 4;   // row 0..31
    const int jq = t & 15;   // j quad -> j = 4*jq .. 4*jq+3

    // MFMA mapping: 8 waves; wave w: M-tile mt = w&1, N-tiles {2*nb, 2*nb+1}, nb = w>>1
    const int lane = t & 63;
    const int w = t >> 6;
    const int mt = w & 1;
    const int nb = w >> 1;
    const int arow = mt * 16 + (lane & 15);
    const int g = lane >> 4;

    const float s1v = s1g[b * NN + i0 + r];

    f32x4 acc[2];
    acc[0] = (f32x4){0.f, 0.f, 0.f, 0.f};
    acc[1] = (f32x4){0.f, 0.f, 0.f, 0.f};
    float ssum = 0.f;

    const int* adjb = adj + (size_t)b * NN * NN + (size_t)i0 * NN;
    const int* aptr = adjb + (size_t)r * NN + jq * 4;
    const unsigned short* whb = whpv + (size_t)b * 32 * 8192;
    const float* s2b = s2g + b * NN;

    // depth-2 prefetch registers
    int4   ac[2];
    short8 wf0[2], wf1[2];
    f32x4  s2r[2];
    ac[0]  = *(const int4*)aptr;
    wf0[0] = *(const short8*)&whb[t * 8];
    wf1[0] = *(const short8*)&whb[4096 + t * 8];
    s2r[0] = *(const f32x4*)&s2b[jq * 4];
    ac[1]  = *(const int4*)(aptr + 64);
    wf0[1] = *(const short8*)&whb[8192 + t * 8];
    wf1[1] = *(const short8*)&whb[8192 + 4096 + t * 8];
    s2r[1] = *(const f32x4*)&s2b[64 + jq * 4];

    const int pbyte = r * 128 + ((jq >> 1) ^ (r & 7)) * 16 + (jq & 1) * 8;
    const int abyte = arow * 128;

    #pragma unroll 2   // makes slot/buf indices compile-time (keeps arrays in registers)
    for (int jc = 0; jc < 32; ++jc) {
        const int slot = jc & 1;
        const int buf  = jc & 1;

        // consume current chunk's regs
        int4   a_  = ac[slot];
        short8 wc0 = wf0[slot];
        short8 wc1 = wf1[slot];
        f32x4  s2v = s2r[slot];

        // issue prefetch for chunk jc+2 into this slot (wraps harmlessly at the end)
        const int jn = (jc + 2) & 31;
        ac[slot]  = *(const int4*)(aptr + jn * 64);
        wf0[slot] = *(const short8*)&whb[(size_t)jn * 8192 + t * 8];
        wf1[slot] = *(const short8*)&whb[(size_t)jn * 8192 + 4096 + t * 8];
        s2r[slot] = *(const f32x4*)&s2b[jn * 64 + jq * 4];

        // compute P (32x64) for current chunk
        float p0, p1, p2, p3;
        {
            float e0 = s1v + s2v[0]; e0 = fmaxf(e0, 0.2f * e0);
            p0 = (a_.x > 0) ? __expf(e0) : 0.f;
            float e1 = s1v + s2v[1]; e1 = fmaxf(e1, 0.2f * e1);
            p1 = (a_.y > 0) ? __expf(e1) : 0.f;
            float e2 = s1v + s2v[2]; e2 = fmaxf(e2, 0.2f * e2);
            p2 = (a_.z > 0) ? __expf(e2) : 0.f;
            float e3 = s1v + s2v[3]; e3 = fmaxf(e3, 0.2f * e3);
            p3 = (a_.w > 0) ? __expf(e3) : 0.f;
        }
        ssum += (p0 + p1) + (p2 + p3);
        unsigned int pk0 = (unsigned int)f2bf(p0) | ((unsigned int)f2bf(p1) << 16);
        unsigned int pk1 = (unsigned int)f2bf(p2) | ((unsigned int)f2bf(p3) << 16);
        uint2 pk = {pk0, pk1};
        *(uint2*)&Plds[buf][pbyte] = pk;

        // write current Wh fragments to LDS
        *(short8*)&BL[buf][t * 8] = wc0;
        *(short8*)&BL[buf][4096 + t * 8] = wc1;

        BAR_LGKM();   // LDS visible; global prefetch stays in flight

        // MFMA on current buffer. Safe vs iter jc+2's writes: every wave executed
        // lgkmcnt(0) (its reads complete) before arriving at barrier jc+1, and the
        // jc+2 writes occur only after barrier jc+1.
        #pragma unroll
        for (int kt = 0; kt < 2; ++kt) {
            int aslot = (4 * kt + g) ^ (arow & 7);
            short8 af = *(const short8*)&Plds[buf][abyte + aslot * 16];
            #pragma unroll
            for (int n = 0; n < 2; ++n) {
                int nt = nb * 2 + n;
                short8 bfr = *(const short8*)&BL[buf][((kt * 8 + nt) * 64 + lane) * 8];
                acc[n] = __builtin_amdgcn_mfma_f32_16x16x32_bf16(af, bfr, acc[n], 0, 0, 0);
            }
        }
    }

    // softmax denominators: reduce over the 16 lanes sharing a row
    {
        float v = ssum;
        #pragma unroll
        for (int m = 8; m >= 1; m >>= 1) v += __shfl_xor(v, m, 64);
        if (jq == 0) Sden[r] = v;
    }
    __syncthreads();

    // epilogue: scale by 1/S, store. D layout: col = lane&15, row = (lane>>4)*4 + reg
    float* ob = out + ((size_t)b * NN + i0) * FOUT;
    #pragma unroll
    for (int n = 0; n < 2; ++n) {
        int col = (nb * 2 + n) * 16 + (lane & 15);
        #pragma unroll
        for (int q = 0; q < 4; ++q) {
            int row = mt * 16 + (lane >> 4) * 4 + q;
            ob[(size_t)row * FOUT + col] = acc[n][q] / Sden[row];
        }
    }
}

extern "C" void kernel_launch(void* const* d_in, const int* in_sizes, int n_in,
                              void* d_out, int out_size, void* d_ws, size_t ws_size,
                              hipStream_t stream) {
    (void)in_sizes; (void)n_in; (void)out_size; (void)ws_size;
    const float* h   = (const float*)d_in[0];
    const int*   adj = (const int*)d_in[1];
    const float* W   = (const float*)d_in[2];
    const float* a   = (const float*)d_in[3];
    float* out = (float*)d_out;

    unsigned short* whpv = (unsigned short*)d_ws;                       // 4 MB bf16 fragments
    float* s1g = (float*)((char*)d_ws + (4u << 20));                    // 64 KB
    float* s2g = (float*)((char*)d_ws + (4u << 20) + (64u << 10));     // 64 KB

    gat_prep<<<dim3(256), dim3(256), 0, stream>>>(h, W, a, whpv, s1g, s2g);
    gat_main<<<dim3(512), dim3(512), 0, stream>>>(adj, whpv, s1g, s2g, out);
}

// Round 4
// 63.755 us; speedup vs baseline: 1.3188x; 1.1896x over previous
//
#include <hip/hip_runtime.h>

#define NB 8
#define NN 2048
#define FIN 256
#define FOUT 128

typedef __attribute__((ext_vector_type(8))) short short8;
typedef __attribute__((ext_vector_type(4))) float f32x4;

static __device__ __forceinline__ unsigned short f2bf(float f) {
    unsigned int u = __float_as_uint(f);
    u += 0x7fffu + ((u >> 16) & 1u);
    return (unsigned short)(u >> 16);
}

// Raw barrier: LDS writes visible (lgkmcnt(0)), but outstanding GLOBAL loads are NOT
// drained (no vmcnt wait) — prefetch stays in flight across the barrier.
#define BAR_LGKM()                                            \
    do {                                                      \
        asm volatile("s_waitcnt lgkmcnt(0)" ::: "memory");    \
        __builtin_amdgcn_sched_barrier(0);                    \
        __builtin_amdgcn_s_barrier();                         \
        __builtin_amdgcn_sched_barrier(0);                    \
    } while (0)

// K1: Wh = h@W (fp32 in regs), emit s1/s2 (fp32) and WhPV (bf16, MFMA-B-fragment layout).
// WhPV layout per 64-j chunk: [kt(2)][nt(8)][lane(64)][i(8)] where element =
//   Wh[j0 + 32*kt + 8*(lane>>4) + i][16*nt + (lane&15)]   (sigma(g,i) = 8g+i)
__global__ __launch_bounds__(256) void gat_prep(
    const float* __restrict__ h, const float* __restrict__ W, const float* __restrict__ a,
    unsigned short* __restrict__ whpv, float* __restrict__ s1g, float* __restrict__ s2g)
{
    __shared__ __align__(16) float hT[64 * FIN];        // 64 KB
    __shared__ __align__(16) unsigned short pvs[8192];  // 16 KB
    const int t = threadIdx.x;
    const int bx = blockIdx.x;
    const int b = bx >> 5;
    const int jt = bx & 31;
    const int j0 = jt * 64;

    const float* hsrc = h + ((size_t)b * NN + j0) * FIN;
    #pragma unroll
    for (int p = 0; p < 16; ++p) {
        int idx = p * 256 + t;
        *(f32x4*)&hT[idx * 4] = *(const f32x4*)&hsrc[idx * 4];
    }
    __syncthreads();

    const int cg = t & 31;   // cols 4cg..4cg+3
    const int rg = t >> 5;   // rows 8rg..8rg+7
    float acc[8][4];
    #pragma unroll
    for (int r = 0; r < 8; ++r)
        #pragma unroll
        for (int q = 0; q < 4; ++q) acc[r][q] = 0.f;

    for (int f = 0; f < FIN; f += 4) {
        f32x4 wv[4];
        #pragma unroll
        for (int q = 0; q < 4; ++q) wv[q] = *(const f32x4*)&W[(f + q) * FOUT + cg * 4];
        #pragma unroll
        for (int r = 0; r < 8; ++r) {
            f32x4 hv = *(const f32x4*)&hT[(rg * 8 + r) * FIN + f];
            #pragma unroll
            for (int q = 0; q < 4; ++q) {
                acc[r][0] += hv[q] * wv[q][0];
                acc[r][1] += hv[q] * wv[q][1];
                acc[r][2] += hv[q] * wv[q][2];
                acc[r][3] += hv[q] * wv[q][3];
            }
        }
    }

    f32x4 a1v = *(const f32x4*)&a[cg * 4];
    f32x4 a2v = *(const f32x4*)&a[FOUT + cg * 4];
    #pragma unroll
    for (int r = 0; r < 8; ++r) {
        float p1 = acc[r][0]*a1v[0] + acc[r][1]*a1v[1] + acc[r][2]*a1v[2] + acc[r][3]*a1v[3];
        float p2 = acc[r][0]*a2v[0] + acc[r][1]*a2v[1] + acc[r][2]*a2v[2] + acc[r][3]*a2v[3];
        #pragma unroll
        for (int m = 16; m >= 1; m >>= 1) {
            p1 += __shfl_xor(p1, m, 64);
            p2 += __shfl_xor(p2, m, 64);
        }
        if (cg == 0) {
            s1g[b * NN + j0 + rg * 8 + r] = p1;
            s2g[b * NN + j0 + rg * 8 + r] = p2;
        }
    }

    #pragma unroll
    for (int r = 0; r < 8; ++r) {
        int jl = rg * 8 + r;
        int kt = jl >> 5, j5 = jl & 31, g = j5 >> 3, i = j5 & 7;
        #pragma unroll
        for (int q = 0; q < 4; ++q) {
            int c = cg * 4 + q;
            int lane = g * 16 + (c & 15);
            int nt = c >> 4;
            pvs[((kt * 8 + nt) * 64 + lane) * 8 + i] = f2bf(acc[r][q]);
        }
    }
    __syncthreads();
    unsigned short* dst = whpv + (size_t)(b * 32 + jt) * 8192;
    #pragma unroll
    for (int p = 0; p < 4; ++p) {
        int idx = p * 2048 + t * 8;
        *(short8*)&dst[idx] = *(const short8*)&pvs[idx];
    }
}

// K2 v4: XCD-affinity block mapping — b = bx & 7 (round-robin dispatch puts all blocks
// of batch b on XCD b), so whpv[b] (4 MB) stays L2-resident and the 268 MB of whpv
// re-reads are served from L2 instead of L3/HBM. Inner structure unchanged from v3.
__global__ __launch_bounds__(512, 4) void gat_main(
    const int* __restrict__ adj, const unsigned short* __restrict__ whpv,
    const float* __restrict__ s1g, const float* __restrict__ s2g, float* __restrict__ out)
{
    __shared__ __align__(16) char Plds[2][32 * 128];       // 2 x 4 KB: [row][slot^ (16B)]
    __shared__ __align__(16) unsigned short BL[2][8192];   // 2 x 16 KB: B fragments
    __shared__ float Sden[32];

    const int t = threadIdx.x;
    const int bx = blockIdx.x;
    const int b = bx & 7;            // XCD id — whpv[b] L2-affinity
    const int i0 = (bx >> 3) * 32;   // i-tile

    // P-compute mapping: one row x 4 j's per thread
    const int r  = t >> 4;   // row 0..31
    const int jq = t & 15;   // j quad -> j = 4*jq .. 4*jq+3

    // MFMA mapping: 8 waves; wave w: M-tile mt = w&1, N-tiles {2*nb, 2*nb+1}, nb = w>>1
    const int lane = t & 63;
    const int w = t >> 6;
    const int mt = w & 1;
    const int nb = w >> 1;
    const int arow = mt * 16 + (lane & 15);
    const int g = lane >> 4;

    const float s1v = s1g[b * NN + i0 + r];

    f32x4 acc[2];
    acc[0] = (f32x4){0.f, 0.f, 0.f, 0.f};
    acc[1] = (f32x4){0.f, 0.f, 0.f, 0.f};
    float ssum = 0.f;

    const int* adjb = adj + (size_t)b * NN * NN + (size_t)i0 * NN;
    const int* aptr = adjb + (size_t)r * NN + jq * 4;
    const unsigned short* whb = whpv + (size_t)b * 32 * 8192;
    const float* s2b = s2g + b * NN;

    // depth-2 prefetch registers
    int4   ac[2];
    short8 wf0[2], wf1[2];
    f32x4  s2r[2];
    ac[0]  = *(const int4*)aptr;
    wf0[0] = *(const short8*)&whb[t * 8];
    wf1[0] = *(const short8*)&whb[4096 + t * 8];
    s2r[0] = *(const f32x4*)&s2b[jq * 4];
    ac[1]  = *(const int4*)(aptr + 64);
    wf0[1] = *(const short8*)&whb[8192 + t * 8];
    wf1[1] = *(const short8*)&whb[8192 + 4096 + t * 8];
    s2r[1] = *(const f32x4*)&s2b[64 + jq * 4];

    const int pbyte = r * 128 + ((jq >> 1) ^ (r & 7)) * 16 + (jq & 1) * 8;
    const int abyte = arow * 128;

    #pragma unroll 2   // makes slot/buf indices compile-time (keeps arrays in registers)
    for (int jc = 0; jc < 32; ++jc) {
        const int slot = jc & 1;
        const int buf  = jc & 1;

        // consume current chunk's regs
        int4   a_  = ac[slot];
        short8 wc0 = wf0[slot];
        short8 wc1 = wf1[slot];
        f32x4  s2v = s2r[slot];

        // issue prefetch for chunk jc+2 into this slot (wraps harmlessly at the end)
        const int jn = (jc + 2) & 31;
        ac[slot]  = *(const int4*)(aptr + jn * 64);
        wf0[slot] = *(const short8*)&whb[(size_t)jn * 8192 + t * 8];
        wf1[slot] = *(const short8*)&whb[(size_t)jn * 8192 + 4096 + t * 8];
        s2r[slot] = *(const f32x4*)&s2b[jn * 64 + jq * 4];

        // compute P (32x64) for current chunk
        float p0, p1, p2, p3;
        {
            float e0 = s1v + s2v[0]; e0 = fmaxf(e0, 0.2f * e0);
            p0 = (a_.x > 0) ? __expf(e0) : 0.f;
            float e1 = s1v + s2v[1]; e1 = fmaxf(e1, 0.2f * e1);
            p1 = (a_.y > 0) ? __expf(e1) : 0.f;
            float e2 = s1v + s2v[2]; e2 = fmaxf(e2, 0.2f * e2);
            p2 = (a_.z > 0) ? __expf(e2) : 0.f;
            float e3 = s1v + s2v[3]; e3 = fmaxf(e3, 0.2f * e3);
            p3 = (a_.w > 0) ? __expf(e3) : 0.f;
        }
        ssum += (p0 + p1) + (p2 + p3);
        unsigned int pk0 = (unsigned int)f2bf(p0) | ((unsigned int)f2bf(p1) << 16);
        unsigned int pk1 = (unsigned int)f2bf(p2) | ((unsigned int)f2bf(p3) << 16);
        uint2 pk = {pk0, pk1};
        *(uint2*)&Plds[buf][pbyte] = pk;

        // write current Wh fragments to LDS
        *(short8*)&BL[buf][t * 8] = wc0;
        *(short8*)&BL[buf][4096 + t * 8] = wc1;

        BAR_LGKM();   // LDS visible; global prefetch stays in flight

        // MFMA on current buffer. Safe vs iter jc+2's writes: every wave executed
        // lgkmcnt(0) (its reads complete) before arriving at barrier jc+1, and the
        // jc+2 writes occur only after barrier jc+1.
        #pragma unroll
        for (int kt = 0; kt < 2; ++kt) {
            int aslot = (4 * kt + g) ^ (arow & 7);
            short8 af = *(const short8*)&Plds[buf][abyte + aslot * 16];
            #pragma unroll
            for (int n = 0; n < 2; ++n) {
                int nt = nb * 2 + n;
                short8 bfr = *(const short8*)&BL[buf][((kt * 8 + nt) * 64 + lane) * 8];
                acc[n] = __builtin_amdgcn_mfma_f32_16x16x32_bf16(af, bfr, acc[n], 0, 0, 0);
            }
        }
    }

    // softmax denominators: reduce over the 16 lanes sharing a row
    {
        float v = ssum;
        #pragma unroll
        for (int m = 8; m >= 1; m >>= 1) v += __shfl_xor(v, m, 64);
        if (jq == 0) Sden[r] = v;
    }
    __syncthreads();

    // epilogue: scale by 1/S, store. D layout: col = lane&15, row = (lane>>4)*4 + reg
    float* ob = out + ((size_t)b * NN + i0) * FOUT;
    #pragma unroll
    for (int n = 0; n < 2; ++n) {
        int col = (nb * 2 + n) * 16 + (lane & 15);
        #pragma unroll
        for (int q = 0; q < 4; ++q) {
            int row = mt * 16 + (lane >> 4) * 4 + q;
            ob[(size_t)row * FOUT + col] = acc[n][q] / Sden[row];
        }
    }
}

extern "C" void kernel_launch(void* const* d_in, const int* in_sizes, int n_in,
                              void* d_out, int out_size, void* d_ws, size_t ws_size,
                              hipStream_t stream) {
    (void)in_sizes; (void)n_in; (void)out_size; (void)ws_size;
    const float* h   = (const float*)d_in[0];
    const int*   adj = (const int*)d_in[1];
    const float* W   = (const float*)d_in[2];
    const float* a   = (const float*)d_in[3];
    float* out = (float*)d_out;

    unsigned short* whpv = (unsigned short*)d_ws;                       // 4 MB bf16 fragments
    float* s1g = (float*)((char*)d_ws + (4u << 20));                    // 64 KB
    float* s2g = (float*)((char*)d_ws + (4u << 20) + (64u << 10));     // 64 KB

    gat_prep<<<dim3(256), dim3(256), 0, stream>>>(h, W, a, whpv, s1g, s2g);
    gat_main<<<dim3(512), dim3(512), 0, stream>>>(adj, whpv, s1g, s2g, out);
}